// Round 16
// baseline (219.617 us; speedup 1.0000x reference)
//
#include <hip/hip_runtime.h>
#include <math.h>

#define BB 4
#define TT 1024
#define CCH 1024
#define HH 16
#define DD 64
#define EE 8
#define HID 128
#define CAP 8192    // entries per (proj,pair) list; mean is 65536/28 ~= 2340
#define GEXP 504    // expert grid size (R16: 1008 regressed — staging
                    // amortization beats tail-trimming; 504 is the optimum)

typedef unsigned short u16;
typedef unsigned int u32;
typedef short bf16x8 __attribute__((ext_vector_type(8)));
typedef short bf16x4 __attribute__((ext_vector_type(4)));
typedef float f32x4 __attribute__((ext_vector_type(4)));
typedef float f32x2 __attribute__((ext_vector_type(2)));

__device__ __forceinline__ u16 f2bf(float f) {          // RNE (final stores)
    unsigned int u = __float_as_uint(f);
    unsigned int r = (u + 0x7FFFu + ((u >> 16) & 1u)) >> 16;
    return (u16)r;
}
// pack 2 floats -> u32 of 2 bf16 (fast round) via v_perm_b32: 3 VALU ops
__device__ __forceinline__ u32 pkbf(float lo, float hi) {
    u32 a = __float_as_uint(lo) + 0x8000u;
    u32 b = __float_as_uint(hi) + 0x8000u;
    return __builtin_amdgcn_perm(b, a, 0x07060302u);
}
// raw v_exp_f32: D = 2^S0 (plain exp2f without fast-math lowers to the
// PRECISE ocml exp2 — a multi-instruction sequence; this is the 1-inst form).
__device__ __forceinline__ float exp2_raw(float x) {
    return __builtin_amdgcn_exp2f(x);
}
// wt * gelu(z) on a float2 — vector-typed arithmetic so the backend can emit
// packed v_pk_{mul,fma,add}_f32 (CDNA4 dual fp32). exp/rcp stay scalar
// (v_exp_f32 / v_rcp_f32 have no packed form). Bit-identical math per lane.
__device__ __forceinline__ f32x2 gelu2w(f32x2 z, float wt) {
    f32x2 t  = z * z;
    f32x2 wn = t * (-0.10294343f) + (f32x2){-2.3022082f, -2.3022082f};
    f32x2 y  = z * wn;
    f32x2 e;
    e.x = exp2_raw(y.x);
    e.y = exp2_raw(y.y);
    f32x2 den = e + 1.f;
    f32x2 r;
    r.x = __builtin_amdgcn_rcpf(den.x);
    r.y = __builtin_amdgcn_rcpf(den.y);
    f32x2 g = z * r;
    return g * wt;
}

// async 16B global -> LDS copy (dest must be wave-uniform base + lane*16)
#define GLD16(gp, lp) __builtin_amdgcn_global_load_lds( \
    (const __attribute__((address_space(1))) u32*)(gp), \
    (__attribute__((address_space(3))) u32*)(lp), 16, 0, 0)

// ============================================================================
// Kernel P: fused prep. Block-range dispatch of three independent roles:
//   [0,192)     wcvt  — expert weight fp32->bf16 images (pre-swizzled)
//   [192,1216)  cvt   — o_w fp32->bf16
//   [1216,1472) router— top-2 routing + inline x fp32->bf16 (the router
//                       already reads every x element; writing xbf here saves
//                       the separate 16 MB re-read a standalone xcvt did)
// w2 image laid out as the K=16 A-operand (w2^T) fragments:
//   [p][e][g(64)][pos(32)][j(4)]  elem@pos = w2[16*(gg>>2)+4*(gg&3)+j][g],
//   pos = gg ^ (g & 31)   (XOR swizzle -> conflict-free ds_read_b64)
// ============================================================================
__global__ __launch_bounds__(256) void prep_kernel(
    const float* __restrict__ x,
    const float* __restrict__ rq, const float* __restrict__ rk, const float* __restrict__ rv,
    unsigned int* __restrict__ counts,
    unsigned int* __restrict__ idxbuf, float2* __restrict__ wtbuf,
    const float* __restrict__ qw1, const float* __restrict__ kw1, const float* __restrict__ vw1,
    const float* __restrict__ qw2, const float* __restrict__ kw2, const float* __restrict__ vw2,
    u16* __restrict__ img1, u16* __restrict__ img2,
    const float* __restrict__ ow, u16* __restrict__ owbf,
    u16* __restrict__ xbf)
{
    const int bi = blockIdx.x;
    const int tid = threadIdx.x;

    if (bi < 192) {
        // ---- wcvt role ----
        //   w1 image: [p][e][f(128)][c(8)][j(8)]  elem = w1[8*(c^(f&7))+j][f]
        int t = bi * 256 + tid;
        if (t < 24576) {
            int c = t & 7, f = (t >> 3) & 127, e = (t >> 10) & 7, p = t >> 13;
            const float* w1 = ((p == 0) ? qw1 : (p == 1) ? kw1 : vw1) + e * 8192;
            int dbase = 8 * (c ^ (f & 7));
            u16 tmp[8];
            #pragma unroll
            for (int j = 0; j < 8; ++j) tmp[j] = f2bf(w1[(dbase + j) * 128 + f]);
            uint4 ov;
            ov.x = (u32)tmp[0] | ((u32)tmp[1] << 16);
            ov.y = (u32)tmp[2] | ((u32)tmp[3] << 16);
            ov.z = (u32)tmp[4] | ((u32)tmp[5] << 16);
            ov.w = (u32)tmp[6] | ((u32)tmp[7] << 16);
            ((uint4*)img1)[t] = ov;
        } else {
            // w2^T A-operand image (see header comment)
            int i = t - 24576;                 // [0, 24576)
            int m = i & 15, g = (i >> 4) & 63, e = (i >> 10) & 7, p = i >> 13;
            const float* w2 = ((p == 0) ? qw2 : (p == 1) ? kw2 : vw2) + e * 8192;
            u16* dstrow = img2 + (p * 8 + e) * 8192 + g * 128;
            #pragma unroll
            for (int u = 0; u < 2; ++u) {
                int gg = 2 * m + u;
                int fbase = 16 * (gg >> 2) + 4 * (gg & 3);
                int pos = gg ^ (g & 31);
                u16 a0 = f2bf(w2[(fbase + 0) * 64 + g]);
                u16 a1 = f2bf(w2[(fbase + 1) * 64 + g]);
                u16 a2 = f2bf(w2[(fbase + 2) * 64 + g]);
                u16 a3 = f2bf(w2[(fbase + 3) * 64 + g]);
                uint2 ov;
                ov.x = (u32)a0 | ((u32)a1 << 16);
                ov.y = (u32)a2 | ((u32)a3 << 16);
                *(uint2*)(dstrow + pos * 4) = ov;
            }
        }
        return;
    }

    if (bi < 1216) {
        // ---- cvt role: o_w fp32 -> bf16 ----
        int i = (bi - 192) * 256 + tid;      // exactly 1024*256 = 262144 float4s
        float4 v = ((const float4*)ow)[i];
        unsigned int lov = (unsigned int)f2bf(v.x) | ((unsigned int)f2bf(v.y) << 16);
        unsigned int hiv = (unsigned int)f2bf(v.z) | ((unsigned int)f2bf(v.w) << 16);
        ((uint2*)owbf)[i] = make_uint2(lov, hiv);
        return;
    }

    // ---- router role (+ inline xbf conversion) ----
    {
        const unsigned int g = (bi - 1216) * 256 + tid;

        __shared__ float rS[3][64][8];
        __shared__ int lcnt[192];
        __shared__ int lbase[192];

        for (int i = tid; i < 1536; i += 256) {
            int p = i >> 9, rem = i & 511;
            const float* rp = (p == 0) ? rq : (p == 1) ? rk : rv;
            rS[p][rem >> 3][rem & 7] = rp[rem];
        }
        if (tid < 192) lcnt[tid] = 0;
        __syncthreads();

        float lg[3][8];
        #pragma unroll
        for (int p = 0; p < 3; ++p)
            #pragma unroll
            for (int e = 0; e < 8; ++e) lg[p][e] = 0.f;

        const float* xr = x + (size_t)g * 64;
        u16* xw = xbf + (size_t)g * 64;
        for (int i4 = 0; i4 < 16; ++i4) {
            float4 xv = ((const float4*)xr)[i4];
            // inline x -> bf16 (fast-round, identical bits to old xcvt)
            uint2 xo;
            xo.x = pkbf(xv.x, xv.y);
            xo.y = pkbf(xv.z, xv.w);
            *(uint2*)(xw + i4 * 4) = xo;
            float xa[4] = {xv.x, xv.y, xv.z, xv.w};
            #pragma unroll
            for (int m = 0; m < 4; ++m) {
                int d = i4 * 4 + m;
                #pragma unroll
                for (int p = 0; p < 3; ++p) {
                    float4 r0 = *(const float4*)&rS[p][d][0];
                    float4 r1 = *(const float4*)&rS[p][d][4];
                    lg[p][0] += xa[m] * r0.x; lg[p][1] += xa[m] * r0.y;
                    lg[p][2] += xa[m] * r0.z; lg[p][3] += xa[m] * r0.w;
                    lg[p][4] += xa[m] * r1.x; lg[p][5] += xa[m] * r1.y;
                    lg[p][6] += xa[m] * r1.z; lg[p][7] += xa[m] * r1.w;
                }
            }
        }

        int ppe[3]; float2 pw[3]; int slot[3];
        #pragma unroll
        for (int p = 0; p < 3; ++p) {
            int i1 = 0; float v1 = lg[p][0];
            #pragma unroll
            for (int e = 1; e < 8; ++e) { if (lg[p][e] > v1) { v1 = lg[p][e]; i1 = e; } }
            int i2 = -1; float v2 = -3.402823466e38f;
            #pragma unroll
            for (int e = 0; e < 8; ++e) { if (e != i1 && lg[p][e] > v2) { v2 = lg[p][e]; i2 = e; } }
            float z = __expf(v2 - v1);
            float inv = 1.f / (1.f + z);
            float wa = inv, wb = z * inv;
            int lo = min(i1, i2), hi = max(i1, i2);
            float wlo = (i1 < i2) ? wa : wb;
            float whi = (i1 < i2) ? wb : wa;
            int pel = p * 64 + lo * 8 + hi;
            ppe[p] = pel; pw[p] = make_float2(wlo, whi);
            slot[p] = atomicAdd(&lcnt[pel], 1);
        }
        __syncthreads();
        if (tid < 192) {
            int c = lcnt[tid];
            lbase[tid] = c ? (int)atomicAdd(&counts[tid], (unsigned int)c) : 0;
        }
        __syncthreads();
        #pragma unroll
        for (int p = 0; p < 3; ++p) {
            int pos = lbase[ppe[p]] + slot[p];
            if (pos < CAP) {
                idxbuf[ppe[p] * CAP + pos] = g;
                wtbuf[ppe[p] * CAP + pos]  = pw[p];
            }
        }
    }
}

// ============================================================================
// Kernel 1b: scheduler. Allocates GEXP blocks across the 84 (proj,pair)
// lists proportionally to subtile count (largest-remainder).
// ============================================================================
__global__ __launch_bounds__(128) void sched_kernel(
    const unsigned int* __restrict__ counts, unsigned int* __restrict__ blockinfo)
{
    const int tid = threadIdx.x;
    __shared__ int nsub[84];
    __shared__ int extra[84];
    __shared__ int frac[84];
    __shared__ int alloc[84];
    __shared__ int startS[84];
    __shared__ int nnzS, totalS, rem2S;

    if (tid < 84) {
        int p = tid / 28, q = tid - 28 * p, lo = 0;
        while (q >= 7 - lo) { q -= 7 - lo; ++lo; }
        int hi = lo + 1 + q;
        int n = (int)counts[p * 64 + lo * 8 + hi];
        if (n > CAP) n = CAP;
        nsub[tid] = (n + 31) >> 5;
    }
    __syncthreads();
    if (tid == 0) {
        int tot = 0, nz = 0;
        for (int i = 0; i < 84; ++i) { tot += nsub[i]; nz += (nsub[i] > 0); }
        totalS = tot; nnzS = nz;
    }
    __syncthreads();
    const int R = GEXP - nnzS;
    if (tid < 84) {
        if (nsub[tid] > 0) {
            int e = (int)(((long long)nsub[tid] * R) / totalS);
            extra[tid] = e;
            frac[tid] = nsub[tid] * R - e * totalS;
        } else { extra[tid] = 0; frac[tid] = -1; }
    }
    __syncthreads();
    if (tid == 0) {
        int se = 0;
        for (int i = 0; i < 84; ++i) se += extra[i];
        rem2S = GEXP - nnzS - se;
    }
    __syncthreads();
    if (tid < 84) {
        if (nsub[tid] > 0) {
            int rank = 0;
            for (int j = 0; j < 84; ++j)
                if (nsub[j] > 0 && (frac[j] > frac[tid] || (frac[j] == frac[tid] && j < tid))) ++rank;
            alloc[tid] = 1 + extra[tid] + (rank < rem2S ? 1 : 0);
        } else alloc[tid] = 0;
    }
    __syncthreads();
    if (tid == 0) {
        int s = 0;
        for (int i = 0; i < 84; ++i) { startS[i] = s; s += alloc[i]; }
    }
    __syncthreads();
    if (tid < 84) {
        int a = alloc[tid], st = startS[tid];
        for (int c = 0; c < a; ++c)
            blockinfo[st + c] = (unsigned)tid | ((unsigned)c << 8) | ((unsigned)a << 20);
    }
}

// ============================================================================
// Kernel 2: pair-grouped expert MLP, bf16 MFMA, wave-independent.
// GEXP=504 (measured optimum), bf16 x gather + packed gelu, rolled ekk loop.
// ============================================================================
__global__ __launch_bounds__(512, 2) void expert_kernel(
    const u16* __restrict__ xbf, const int* __restrict__ pos_ids,
    const float* __restrict__ cosb, const float* __restrict__ sinb,
    const u16* __restrict__ img1, const u16* __restrict__ img2,
    const unsigned int* __restrict__ counts,
    const unsigned int* __restrict__ idxbuf, const float2* __restrict__ wtbuf,
    const unsigned int* __restrict__ blockinfo,
    u16* __restrict__ qb, u16* __restrict__ kb, u16* __restrict__ vb)
{
    const int tid = threadIdx.x;
    const unsigned int info = blockinfo[blockIdx.x];
    const int pe84 = info & 255;
    const int chunk = (info >> 8) & 0xFFF;
    const int nch = info >> 20;
    const int p = pe84 / 28;
    int q28 = pe84 - p * 28;
    int lo = 0;
    while (q28 >= 7 - lo) { q28 -= 7 - lo; ++lo; }
    const int hi = lo + 1 + q28;
    const int pe = p * 64 + lo * 8 + hi;

    int n = (int)counts[pe]; if (n == 0) return; if (n > CAP) n = CAP;

    u16* outp = (p == 0) ? qb : (p == 1) ? kb : vb;
    const unsigned int* il = idxbuf + pe * CAP;
    const float2* wl = wtbuf + pe * CAP;

    __shared__ __align__(16) u16 wsh[32768];   // [e]{ w1 8192 | w2 8192 }  64 KB

    {   // linear DMA staging: images are byte-identical to LDS layout
        const u16* a0 = img1 + (p * 8 + lo) * 8192;
        const u16* b0 = img2 + (p * 8 + lo) * 8192;
        const u16* a1 = img1 + (p * 8 + hi) * 8192;
        const u16* b1 = img2 + (p * 8 + hi) * 8192;
        #pragma unroll
        for (int k = 0; k < 2; ++k) {
            int o = (k * 512 + tid) * 8;
            GLD16(a0 + o, wsh + o);
            GLD16(b0 + o, wsh + 8192 + o);
            GLD16(a1 + o, wsh + 16384 + o);
            GLD16(b1 + o, wsh + 24576 + o);
        }
    }
    __syncthreads();

    const int lane = tid & 63, w = tid >> 6, quad = lane >> 4, m16 = lane & 15;
    const int f7 = m16 & 7;
    const int wid = chunk * 8 + w;
    const int WRK = nch * 8;
    const int nsub = (n + 31) >> 5;

    for (int s = wid; s < nsub; s += WRK) {
        const int base = s * 32;
        unsigned int gtok = 0, obase = 0; float wlo_ = 0.f, whi_ = 0.f;
        int posv = 0, valid = 0;
        if (lane < 32) {
            int j = base + lane;
            valid = (j < n);
            int jc = valid ? j : (n - 1);
            gtok = il[jc];
            float2 wv = wl[jc];
            wlo_ = valid ? wv.x : 0.f; whi_ = valid ? wv.y : 0.f;
            unsigned int b_ = gtok >> 14, h_ = gtok & 15, t_ = (gtok >> 4) & 1023;
            obase = ((b_ * 16 + h_) * 1024 + t_) * 64;
            posv = pos_ids[b_ * 1024 + t_];
        }

        // per-(e, mt2) router weight for this lane's token column (m16)
        float wf00 = __shfl(wlo_, m16, 64);
        float wf10 = __shfl(whi_, m16, 64);
        float wf01 = __shfl(wlo_, 16 + m16, 64);
        float wf11 = __shfl(whi_, 16 + m16, 64);

        bf16x8 Afr[2][2];
        #pragma unroll
        for (int mt2 = 0; mt2 < 2; ++mt2) {
            unsigned int gm = (unsigned int)__shfl((int)gtok, mt2 * 16 + m16, 64);
            const u16* xr = xbf + (size_t)gm * 64 + 8 * quad;
            Afr[mt2][0] = *(const bf16x8*)(xr);
            Afr[mt2][1] = *(const bf16x8*)(xr + 32);
        }

        f32x4 acc2[2][4];   // [mt2][nt2] — out'[g][tok], router weights pre-folded
        #pragma unroll
        for (int mt2 = 0; mt2 < 2; ++mt2)
            #pragma unroll
            for (int nt = 0; nt < 4; ++nt) acc2[mt2][nt] = (f32x4){0.f, 0.f, 0.f, 0.f};

        // Rolled loop over (e, kk): 8 iterations, body unrolled inside.
        #pragma unroll 1
        for (int ekk = 0; ekk < 8; ++ekk) {
            const int e = ekk >> 2;
            const int kk = ekk & 3;
            const u16* w1b = wsh + e * 16384;
            const u16* w2b = w1b + 8192;
            const float wt0 = e ? wf10 : wf00;
            const float wt1 = e ? wf11 : wf01;

            // --- GEMM1 swapped: C'[f][tok], row=f(4*quad+r), col=tok(m16)
            f32x4 c[2][2];   // [ntl][mt2]
            #pragma unroll
            for (int ntl = 0; ntl < 2; ++ntl) {
                const int f = 16 * (2 * kk + ntl) + m16;
                const u16* w1f = w1b + f * 64;
                bf16x8 wa = *(const bf16x8*)(w1f + (((quad    ) ^ f7) << 3));
                bf16x8 wb = *(const bf16x8*)(w1f + (((quad + 4) ^ f7) << 3));
                #pragma unroll
                for (int mt2 = 0; mt2 < 2; ++mt2) {
                    f32x4 t = (f32x4){0.f, 0.f, 0.f, 0.f};
                    t = __builtin_amdgcn_mfma_f32_16x16x32_bf16(wa, Afr[mt2][0], t, 0, 0, 0);
                    c[ntl][mt2] = __builtin_amdgcn_mfma_f32_16x16x32_bf16(wb, Afr[mt2][1], t, 0, 0, 0);
                }
            }

            // --- A2 (w2^T) K=16 fragments: mt2-invariant, loaded once
            bf16x4 w2f[2][4];   // [ntl][nt2]
            #pragma unroll
            for (int ntl = 0; ntl < 2; ++ntl) {
                const int gg = 4 * (2 * kk + ntl) + quad;
                #pragma unroll
                for (int nt2 = 0; nt2 < 4; ++nt2) {
                    const int g = 16 * nt2 + m16;
                    const int pos = gg ^ (g & 31);
                    w2f[ntl][nt2] = *(const bf16x4*)(w2b + g * 128 + pos * 4);
                }
            }

            // --- packed gelu+scale, pack to bf16, GEMM2 = mfma16(w2^T, h)
            #pragma unroll
            for (int mt2 = 0; mt2 < 2; ++mt2) {
                const float wt = mt2 ? wt1 : wt0;
                #pragma unroll
                for (int ntl = 0; ntl < 2; ++ntl) {
                    f32x2 z01 = {c[ntl][mt2][0], c[ntl][mt2][1]};
                    f32x2 z23 = {c[ntl][mt2][2], c[ntl][mt2][3]};
                    f32x2 g01 = gelu2w(z01, wt);
                    f32x2 g23 = gelu2w(z23, wt);
                    union { u32 u[2]; bf16x4 v; } bf_;
                    bf_.u[0] = pkbf(g01.x, g01.y);
                    bf_.u[1] = pkbf(g23.x, g23.y);
                    #pragma unroll
                    for (int nt2 = 0; nt2 < 4; ++nt2)
                        acc2[mt2][nt2] = __builtin_amdgcn_mfma_f32_16x16x16bf16_1k(
                            w2f[ntl][nt2], bf_.v, acc2[mt2][nt2], 0, 0, 0);
                }
            }
        }

        // Epilogue: lane (quad,m16) owns token mt2*16+m16, g = 16*nt2+4*quad+reg.
        #pragma unroll
        for (int mt2 = 0; mt2 < 2; ++mt2) {
            const int tk = mt2 * 16 + m16;
            int   pos_r = __shfl(posv, tk, 64);
            unsigned int ob = (unsigned int)__shfl((int)obase, tk, 64);
            int   val_r = __shfl(valid, tk, 64);
            if (p < 2) {
                #pragma unroll
                for (int ntp = 0; ntp < 2; ++ntp) {
                    const int d0 = 16 * ntp + 4 * quad;
                    float4 cv = *(const float4*)&cosb[pos_r * 64 + d0];
                    float4 sv = *(const float4*)&sinb[pos_r * 64 + d0];
                    float o1[4], o2[4];
                    #pragma unroll
                    for (int r = 0; r < 4; ++r) {
                        float v1 = acc2[mt2][ntp][r];
                        float v2 = acc2[mt2][ntp + 2][r];
                        float cd = (&cv.x)[r], sd = (&sv.x)[r];
                        o1[r] = v1 * cd - v2 * sd;
                        o2[r] = v2 * cd + v1 * sd;
                    }
                    if (val_r) {
                        uint2 s1, s2;
                        s1.x = (u32)f2bf(o1[0]) | ((u32)f2bf(o1[1]) << 16);
                        s1.y = (u32)f2bf(o1[2]) | ((u32)f2bf(o1[3]) << 16);
                        s2.x = (u32)f2bf(o2[0]) | ((u32)f2bf(o2[1]) << 16);
                        s2.y = (u32)f2bf(o2[2]) | ((u32)f2bf(o2[3]) << 16);
                        *(uint2*)&outp[ob + d0]      = s1;
                        *(uint2*)&outp[ob + d0 + 32] = s2;
                    }
                }
            } else {
                if (val_r) {
                    #pragma unroll
                    for (int nt2 = 0; nt2 < 4; ++nt2) {
                        uint2 s1;
                        s1.x = (u32)f2bf(acc2[mt2][nt2][0]) | ((u32)f2bf(acc2[mt2][nt2][1]) << 16);
                        s1.y = (u32)f2bf(acc2[mt2][nt2][2]) | ((u32)f2bf(acc2[mt2][nt2][3]) << 16);
                        *(uint2*)&outp[ob + 16 * nt2 + 4 * quad] = s1;
                    }
                }
            }
        }
    }
}

// ============================================================================
// Kernel 4: flash attention. Swapped QK^T (S^T layout), in-register P^T,
// PV via mfma16(V^T, P^T), base-2 softmax via raw v_exp_f32, double-buffered
// K/V LDS (one barrier/iter). Paired q-tiles.
// ============================================================================
__global__ __launch_bounds__(256) void attn_kernel(
    const u16* __restrict__ qbp, const u16* __restrict__ kbp,
    const u16* __restrict__ vbp, u16* __restrict__ ao)
{
    const int tid = threadIdx.x;
    const int i8 = blockIdx.x & 7;
    const int plane_i = blockIdx.x >> 3;           // 64 planes
    const int h = plane_i & 15, b = plane_i >> 4;
    const size_t plane = (size_t)plane_i * 1024 * 64;
    const u16* qp = qbp + plane;
    const u16* kp = kbp + plane;
    const u16* vp = vbp + plane;

    const int w = tid >> 6, lane = tid & 63, quad = lane >> 4, m16 = lane & 15;
    const int row = tid >> 2, seg = tid & 3;       // K staging coords
    const int kjv = tid & 63, dgv = tid >> 6;      // V staging coords

    __shared__ u16 Ks[2][64][72];
    __shared__ u16 Vt[2][64][72];     // [buf][d][kj]
    __shared__ u16 Ps[4][16][72];     // per-wave O^T transpose scratch

    #pragma unroll 1
    for (int half = 0; half < 2; ++half) {
        const int qt = half ? (15 - i8) : i8;
        const int q0 = qt * 64;

        const u16* qrow = &qp[(size_t)(q0 + 16 * w + m16) * 64 + 8 * quad];
        bf16x8 aq0 = *(const bf16x8*)(qrow);
        bf16x8 aq1 = *(const bf16x8*)(qrow + 32);

        uint4 kr0, kr1; ushort4 vr0, vr1, vr2, vr3;
        {   // load tile 0 and commit straight to buf0
            const uint4* src = (const uint4*)&kp[(size_t)row * 64 + seg * 16];
            kr0 = src[0]; kr1 = src[1];
            const u16* vb2 = &vp[(size_t)kjv * 64 + dgv * 4];
            vr0 = *(const ushort4*)(vb2);
            vr1 = *(const ushort4*)(vb2 + 16);
            vr2 = *(const ushort4*)(vb2 + 32);
            vr3 = *(const ushort4*)(vb2 + 48);
            uint4* dst = (uint4*)&Ks[0][row][seg * 16];
            dst[0] = kr0; dst[1] = kr1;
            int d0 = dgv * 4;
            Vt[0][d0 + 0][kjv] = vr0.x; Vt[0][d0 + 1][kjv] = vr0.y;
            Vt[0][d0 + 2][kjv] = vr0.z; Vt[0][d0 + 3][kjv] = vr0.w;
            Vt[0][d0 + 16][kjv] = vr1.x; Vt[0][d0 + 17][kjv] = vr1.y;
            Vt[0][d0 + 18][kjv] = vr1.z; Vt[0][d0 + 19][kjv] = vr1.w;
            Vt[0][d0 + 32][kjv] = vr2.x; Vt[0][d0 + 33][kjv] = vr2.y;
            Vt[0][d0 + 34][kjv] = vr2.z; Vt[0][d0 + 35][kjv] = vr2.w;
            Vt[0][d0 + 48][kjv] = vr3.x; Vt[0][d0 + 49][kjv] = vr3.y;
            Vt[0][d0 + 50][kjv] = vr3.z; Vt[0][d0 + 51][kjv] = vr3.w;
        }
        if (qt > 0) {   // preload tile 1 into registers
            const uint4* src = (const uint4*)&kp[(size_t)(64 + row) * 64 + seg * 16];
            kr0 = src[0]; kr1 = src[1];
            const u16* vb2 = &vp[(size_t)(64 + kjv) * 64 + dgv * 4];
            vr0 = *(const ushort4*)(vb2);
            vr1 = *(const ushort4*)(vb2 + 16);
            vr2 = *(const ushort4*)(vb2 + 32);
            vr3 = *(const ushort4*)(vb2 + 48);
        }
        __syncthreads();

        float m_s = -1e30f, l_s = 0.f;     // this lane's q = 16*w + m16
        f32x4 oacc[4];                     // O^T[d = 16*dt + 4*quad + reg][q]
        #pragma unroll
        for (int i = 0; i < 4; ++i) oacc[i] = (f32x4){0.f, 0.f, 0.f, 0.f};

        const int qrow_l = 16 * w + m16;   // tile-local q row of this lane

        for (int kt = 0; kt <= qt; ++kt) {
            const int cur = kt & 1;
            if (kt < qt) {   // commit prefetched tile kt+1 to the other buffer
                const int nxt = cur ^ 1;     // overlaps with compute below
                uint4* dst = (uint4*)&Ks[nxt][row][seg * 16];
                dst[0] = kr0; dst[1] = kr1;
                int d0 = dgv * 4;
                Vt[nxt][d0 + 0][kjv] = vr0.x; Vt[nxt][d0 + 1][kjv] = vr0.y;
                Vt[nxt][d0 + 2][kjv] = vr0.z; Vt[nxt][d0 + 3][kjv] = vr0.w;
                Vt[nxt][d0 + 16][kjv] = vr1.x; Vt[nxt][d0 + 17][kjv] = vr1.y;
                Vt[nxt][d0 + 18][kjv] = vr1.z; Vt[nxt][d0 + 19][kjv] = vr1.w;
                Vt[nxt][d0 + 32][kjv] = vr2.x; Vt[nxt][d0 + 33][kjv] = vr2.y;
                Vt[nxt][d0 + 34][kjv] = vr2.z; Vt[nxt][d0 + 35][kjv] = vr2.w;
                Vt[nxt][d0 + 48][kjv] = vr3.x; Vt[nxt][d0 + 49][kjv] = vr3.y;
                Vt[nxt][d0 + 50][kjv] = vr3.z; Vt[nxt][d0 + 51][kjv] = vr3.w;
                if (kt + 1 < qt) {   // load tile kt+2 into registers
                    const int k0n = (kt + 2) * 64;
                    const uint4* src = (const uint4*)&kp[(size_t)(k0n + row) * 64 + seg * 16];
                    kr0 = src[0]; kr1 = src[1];
                    const u16* vb2 = &vp[(size_t)(k0n + kjv) * 64 + dgv * 4];
                    vr0 = *(const ushort4*)(vb2);
                    vr1 = *(const ushort4*)(vb2 + 16);
                    vr2 = *(const ushort4*)(vb2 + 32);
                    vr3 = *(const ushort4*)(vb2 + 48);
                }
            }

            // QK^T swapped: S^T[k = 16ct + 4quad + reg][q = 16w + m16]
            f32x4 sv[4];
            #pragma unroll
            for (int ct = 0; ct < 4; ++ct) {
                bf16x8 bk0 = *(const bf16x8*)&Ks[cur][16 * ct + m16][8 * quad];
                bf16x8 bk1 = *(const bf16x8*)&Ks[cur][16 * ct + m16][32 + 8 * quad];
                f32x4 acc = (f32x4){0.f, 0.f, 0.f, 0.f};
                acc = __builtin_amdgcn_mfma_f32_16x16x32_bf16(bk0, aq0, acc, 0, 0, 0);
                acc = __builtin_amdgcn_mfma_f32_16x16x32_bf16(bk1, aq1, acc, 0, 0, 0);
                sv[ct] = acc;
            }

            float s[4][4];
            const bool diag = (kt == qt);
            #pragma unroll
            for (int ct = 0; ct < 4; ++ct)
                #pragma unroll
                for (int reg = 0; reg < 4; ++reg) {
                    float v = sv[ct][reg] * 0.18033688f;   // 0.125 * log2(e)
                    if (diag) {
                        int krow = 16 * ct + 4 * quad + reg;
                        if (krow > qrow_l) v = -1e30f;
                    }
                    s[ct][reg] = v;
                }

            // softmax per q (base-2): lane-local 16-max + 2 shuffles across quad
            float rm = s[0][0];
            #pragma unroll
            for (int ct = 0; ct < 4; ++ct)
                #pragma unroll
                for (int reg = 0; reg < 4; ++reg) rm = fmaxf(rm, s[ct][reg]);
            rm = fmaxf(rm, __shfl_xor(rm, 16, 64));
            rm = fmaxf(rm, __shfl_xor(rm, 32, 64));
            float mn = fmaxf(m_s, rm);
            float al = exp2_raw(m_s - mn);
            float sum = 0.f;
            #pragma unroll
            for (int ct = 0; ct < 4; ++ct)
                #pragma unroll
                for (int reg = 0; reg < 4; ++reg) {
                    float pv = exp2_raw(s[ct][reg] - mn);
                    s[ct][reg] = pv;
                    sum += pv;
                }
            sum += __shfl_xor(sum, 16, 64);
            sum += __shfl_xor(sum, 32, 64);
            l_s = l_s * al + sum;
            m_s = mn;

            // P^T bf16 fragments (K=16 B-operand), in-register
            bf16x4 pt[4];
            #pragma unroll
            for (int ct = 0; ct < 4; ++ct) {
                union { u32 u[2]; bf16x4 v; } pb;
                pb.u[0] = pkbf(s[ct][0], s[ct][1]);
                pb.u[1] = pkbf(s[ct][2], s[ct][3]);
                pt[ct] = pb.v;
            }

            #pragma unroll
            for (int dt = 0; dt < 4; ++dt)
                #pragma unroll
                for (int reg = 0; reg < 4; ++reg) oacc[dt][reg] *= al;

            // PV: O^T[d][q] += V^T_frag x P^T_frag  (K=16 per k-strip ct)
            #pragma unroll
            for (int dt = 0; dt < 4; ++dt) {
                #pragma unroll
                for (int ct = 0; ct < 4; ++ct) {
                    bf16x4 vf = *(const bf16x4*)&Vt[cur][16 * dt + m16][16 * ct + 4 * quad];
                    oacc[dt] = __builtin_amdgcn_mfma_f32_16x16x16bf16_1k(vf, pt[ct], oacc[dt], 0, 0, 0);
                }
            }

            __syncthreads();   // buf[cur] reads done; buf[cur^1] writes visible
        }

        // O^T -> O transpose via per-wave LDS scratch, then coalesced store
        float linv = 1.f / l_s;
        #pragma unroll
        for (int dt = 0; dt < 4; ++dt) {
            u32 lo = (u32)f2bf(oacc[dt][0] * linv) | ((u32)f2bf(oacc[dt][1] * linv) << 16);
            u32 hi = (u32)f2bf(oacc[dt][2] * linv) | ((u32)f2bf(oacc[dt][3] * linv) << 16);
            *(u32*)&Ps[w][m16][16 * dt + 4 * quad]     = lo;
            *(u32*)&Ps[w][m16][16 * dt + 4 * quad + 2] = hi;
        }
        __syncthreads();
        #pragma unroll
        for (int reg = 0; reg < 4; ++reg) {
            int rw = q0 + 16 * w + 4 * quad + reg;
            size_t base = ((size_t)(b * 1024) + rw) * 1024 + h * 64;
            #pragma unroll
            for (int dt = 0; dt < 4; ++dt)
                ao[base + 16 * dt + m16] = Ps[w][4 * quad + reg][16 * dt + m16];
        }
        __syncthreads();   // Ps reads done before next half reuses buffers
    }
}

// ============================================================================
// Kernel 5: output projection, bf16 MFMA gemm_bt. 128x64 tiles, 512 blocks
// (2/CU, 8 waves/CU), register-prefetch pipeline, LDS rows padded to 40 u16.
// ============================================================================
__global__ __launch_bounds__(256) void oproj_kernel(
    const u16* __restrict__ A, const u16* __restrict__ Bw,
    float* __restrict__ out)
{
    const int tid = threadIdx.x;
    const int bn = blockIdx.x & 15;
    const int bm = blockIdx.x >> 4;
    const int m0 = bm * 128, n0 = bn * 64;
    const int w = tid >> 6, lane = tid & 63, quad = lane >> 4, m16 = lane & 15;
    const int wm = (w >> 1) * 64, wn = (w & 1) * 32;

    __shared__ u16 As[128][40];
    __shared__ u16 Bs[64][40];

    const int arw = tid >> 1, asg = (tid & 1) * 16;
    const int brw = tid >> 2, bsg = (tid & 3) * 8;
    const u16* srcA = A + (size_t)(m0 + arw) * 1024 + asg;
    const u16* srcB = Bw + (size_t)(n0 + brw) * 1024 + bsg;

    f32x4 acc[4][2];
    #pragma unroll
    for (int mt = 0; mt < 4; ++mt)
        #pragma unroll
        for (int nt = 0; nt < 2; ++nt) acc[mt][nt] = (f32x4){0.f, 0.f, 0.f, 0.f};

    uint4 pa0 = ((const uint4*)srcA)[0];
    uint4 pa1 = ((const uint4*)srcA)[1];
    uint4 pb0 = *(const uint4*)srcB;

    for (int k0 = 0; k0 < 1024; k0 += 32) {
        __syncthreads();
        *(uint4*)&As[arw][asg]     = pa0;
        *(uint4*)&As[arw][asg + 8] = pa1;
        *(uint4*)&Bs[brw][bsg]     = pb0;
        __syncthreads();
        if (k0 + 32 < 1024) {
            pa0 = ((const uint4*)(srcA + k0 + 32))[0];
            pa1 = ((const uint4*)(srcA + k0 + 32))[1];
            pb0 = *(const uint4*)(srcB + k0 + 32);
        }
        bf16x8 af[4], bfr[2];
        #pragma unroll
        for (int mt = 0; mt < 4; ++mt) af[mt] = *(const bf16x8*)&As[wm + 16 * mt + m16][8 * quad];
        #pragma unroll
        for (int nt = 0; nt < 2; ++nt) bfr[nt] = *(const bf16x8*)&Bs[wn + 16 * nt + m16][8 * quad];
        #pragma unroll
        for (int mt = 0; mt < 4; ++mt)
            #pragma unroll
            for (int nt = 0; nt < 2; ++nt)
                acc[mt][nt] = __builtin_amdgcn_mfma_f32_16x16x32_bf16(af[mt], bfr[nt], acc[mt][nt], 0, 0, 0);
    }
    #pragma unroll
    for (int mt = 0; mt < 4; ++mt)
        #pragma unroll
        for (int nt = 0; nt < 2; ++nt)
            #pragma unroll
            for (int reg = 0; reg < 4; ++reg)
                out[(size_t)(m0 + wm + 16 * mt + 4 * quad + reg) * 1024 + n0 + wn + 16 * nt + m16] =
                    acc[mt][nt][reg];
}

// ============================================================================
extern "C" void kernel_launch(void* const* d_in, const int* in_sizes, int n_in,
                              void* d_out, int out_size, void* d_ws, size_t ws_size,
                              hipStream_t stream) {
    (void)in_sizes; (void)n_in; (void)out_size; (void)ws_size;
    const float* x    = (const float*)d_in[0];
    const int*   pid  = (const int*)  d_in[1];
    const float* cosb = (const float*)d_in[2];
    const float* sinb = (const float*)d_in[3];
    const float* rq   = (const float*)d_in[4];
    const float* rk   = (const float*)d_in[5];
    const float* rv   = (const float*)d_in[6];
    const float* qw1  = (const float*)d_in[7];
    const float* qw2  = (const float*)d_in[8];
    const float* kw1  = (const float*)d_in[9];
    const float* kw2  = (const float*)d_in[10];
    const float* vw1  = (const float*)d_in[11];
    const float* vw2  = (const float*)d_in[12];
    const float* ow   = (const float*)d_in[13];
    float* out = (float*)d_out;

    const size_t MB = 1u << 20;
    char* wsb = (char*)d_ws;
    u16* qb   = (u16*)(wsb + 0 * MB);      // 8 MB  bf16 [B,H,T,D]
    u16* kb   = (u16*)(wsb + 8 * MB);      // 8 MB
    u16* vb   = (u16*)(wsb + 16 * MB);     // 8 MB
    // xbf and aobf SHARE [24,32) MB: prep writes xbf -> expert reads xbf ->
    // attn overwrites region with aobf -> oproj reads aobf. Strictly ordered
    // on one stream, so no conflict (saves 8 MB of workspace).
    u16* xbf  = (u16*)(wsb + 24 * MB);     // 8 MB  bf16 x  [B,T,C]
    u16* aobf = (u16*)(wsb + 24 * MB);     // 8 MB  bf16 attn-out [B,T,C]
    u16* owbf = (u16*)(wsb + 32 * MB);     // 2 MB  bf16 o_w
    unsigned int* idxbuf = (unsigned int*)(wsb + 34 * MB);       // 6 MB
    float2*       wtbuf  = (float2*)(wsb + 41 * MB);             // 12 MB
    unsigned int* counts = (unsigned int*)(wsb + 54 * MB);       // 768 B
    unsigned int* blockinfo = (unsigned int*)(wsb + 54 * MB + 4096); // 2 KB
    u16* w1img = (u16*)(wsb + 56 * MB);    // 384 KB  bf16 w1 LDS images
    u16* w2img = (u16*)(wsb + 57 * MB);    // 384 KB  bf16 w2^T LDS images

    hipMemsetAsync(counts, 0, 1024, stream);

    hipLaunchKernelGGL(prep_kernel, dim3(1472), dim3(256), 0, stream,
                       x, rq, rk, rv, counts, idxbuf, wtbuf,
                       qw1, kw1, vw1, qw2, kw2, vw2, w1img, w2img,
                       ow, owbf, xbf);
    hipLaunchKernelGGL(sched_kernel, dim3(1), dim3(128), 0, stream,
                       counts, blockinfo);
    hipLaunchKernelGGL(expert_kernel, dim3(GEXP), dim3(512), 0, stream,
                       xbf, pid, cosb, sinb, w1img, w2img,
                       counts, idxbuf, wtbuf, blockinfo, qb, kb, vb);
    hipLaunchKernelGGL(attn_kernel, dim3(512), dim3(256), 0, stream,
                       qb, kb, vb, aobf);
    hipLaunchKernelGGL(oproj_kernel, dim3(512), dim3(256), 0, stream,
                       aobf, owbf, out);
}

// Round 17
// 208.427 us; speedup vs baseline: 1.0537x; 1.0537x over previous
//
#include <hip/hip_runtime.h>
#include <math.h>

#define BB 4
#define TT 1024
#define CCH 1024
#define HH 16
#define DD 64
#define EE 8
#define HID 128
#define CAP 8192    // entries per (proj,pair) list; mean is 65536/28 ~= 2340
#define GEXP 504    // expert grid size (measured optimum)

typedef unsigned short u16;
typedef unsigned int u32;
typedef short bf16x8 __attribute__((ext_vector_type(8)));
typedef short bf16x4 __attribute__((ext_vector_type(4)));
typedef float f32x4 __attribute__((ext_vector_type(4)));
typedef float f32x2 __attribute__((ext_vector_type(2)));

__device__ __forceinline__ u16 f2bf(float f) {          // RNE (final stores)
    unsigned int u = __float_as_uint(f);
    unsigned int r = (u + 0x7FFFu + ((u >> 16) & 1u)) >> 16;
    return (u16)r;
}
// pack 2 floats -> u32 of 2 bf16 (fast round) via v_perm_b32: 3 VALU ops
__device__ __forceinline__ u32 pkbf(float lo, float hi) {
    u32 a = __float_as_uint(lo) + 0x8000u;
    u32 b = __float_as_uint(hi) + 0x8000u;
    return __builtin_amdgcn_perm(b, a, 0x07060302u);
}
// raw v_exp_f32: D = 2^S0 (plain exp2f without fast-math lowers to the
// PRECISE ocml exp2 — a multi-instruction sequence; this is the 1-inst form).
__device__ __forceinline__ float exp2_raw(float x) {
    return __builtin_amdgcn_exp2f(x);
}
// wt * gelu(z) on a float2 — vector-typed arithmetic so the backend can emit
// packed v_pk_{mul,fma,add}_f32 (CDNA4 dual fp32). exp/rcp stay scalar
// (v_exp_f32 / v_rcp_f32 have no packed form). Bit-identical math per lane.
__device__ __forceinline__ f32x2 gelu2w(f32x2 z, float wt) {
    f32x2 t  = z * z;
    f32x2 wn = t * (-0.10294343f) + (f32x2){-2.3022082f, -2.3022082f};
    f32x2 y  = z * wn;
    f32x2 e;
    e.x = exp2_raw(y.x);
    e.y = exp2_raw(y.y);
    f32x2 den = e + 1.f;
    f32x2 r;
    r.x = __builtin_amdgcn_rcpf(den.x);
    r.y = __builtin_amdgcn_rcpf(den.y);
    f32x2 g = z * r;
    return g * wt;
}

// async 16B global -> LDS copy (dest must be wave-uniform base + lane*16)
#define GLD16(gp, lp) __builtin_amdgcn_global_load_lds( \
    (const __attribute__((address_space(1))) u32*)(gp), \
    (__attribute__((address_space(3))) u32*)(lp), 16, 0, 0)

// ============================================================================
// Kernel P: fused prep. Block-range dispatch of four independent roles:
//   [0,192)     wcvt  — expert weight fp32->bf16 images (pre-swizzled)
//   [192,1216)  cvt   — o_w fp32->bf16
//   [1216,1472) router— top-2 routing, binned by (proj, expert-pair)
//   [1472,3520) xcvt  — x fp32->bf16 (coalesced 16B/lane stores; R17: the
//                       router-inline fold regressed ~10us — producer write
//                       coalescing matters even for L2-absorbed buffers)
// w2 image laid out as the K=16 A-operand (w2^T) fragments:
//   [p][e][g(64)][pos(32)][j(4)]  elem@pos = w2[16*(gg>>2)+4*(gg&3)+j][g],
//   pos = gg ^ (g & 31)   (XOR swizzle -> conflict-free ds_read_b64)
// ============================================================================
__global__ __launch_bounds__(256) void prep_kernel(
    const float* __restrict__ x,
    const float* __restrict__ rq, const float* __restrict__ rk, const float* __restrict__ rv,
    unsigned int* __restrict__ counts,
    unsigned int* __restrict__ idxbuf, float2* __restrict__ wtbuf,
    const float* __restrict__ qw1, const float* __restrict__ kw1, const float* __restrict__ vw1,
    const float* __restrict__ qw2, const float* __restrict__ kw2, const float* __restrict__ vw2,
    u16* __restrict__ img1, u16* __restrict__ img2,
    const float* __restrict__ ow, u16* __restrict__ owbf,
    u16* __restrict__ xbf)
{
    const int bi = blockIdx.x;
    const int tid = threadIdx.x;

    if (bi < 192) {
        // ---- wcvt role ----
        //   w1 image: [p][e][f(128)][c(8)][j(8)]  elem = w1[8*(c^(f&7))+j][f]
        int t = bi * 256 + tid;
        if (t < 24576) {
            int c = t & 7, f = (t >> 3) & 127, e = (t >> 10) & 7, p = t >> 13;
            const float* w1 = ((p == 0) ? qw1 : (p == 1) ? kw1 : vw1) + e * 8192;
            int dbase = 8 * (c ^ (f & 7));
            u16 tmp[8];
            #pragma unroll
            for (int j = 0; j < 8; ++j) tmp[j] = f2bf(w1[(dbase + j) * 128 + f]);
            uint4 ov;
            ov.x = (u32)tmp[0] | ((u32)tmp[1] << 16);
            ov.y = (u32)tmp[2] | ((u32)tmp[3] << 16);
            ov.z = (u32)tmp[4] | ((u32)tmp[5] << 16);
            ov.w = (u32)tmp[6] | ((u32)tmp[7] << 16);
            ((uint4*)img1)[t] = ov;
        } else {
            // w2^T A-operand image (see header comment)
            int i = t - 24576;                 // [0, 24576)
            int m = i & 15, g = (i >> 4) & 63, e = (i >> 10) & 7, p = i >> 13;
            const float* w2 = ((p == 0) ? qw2 : (p == 1) ? kw2 : vw2) + e * 8192;
            u16* dstrow = img2 + (p * 8 + e) * 8192 + g * 128;
            #pragma unroll
            for (int u = 0; u < 2; ++u) {
                int gg = 2 * m + u;
                int fbase = 16 * (gg >> 2) + 4 * (gg & 3);
                int pos = gg ^ (g & 31);
                u16 a0 = f2bf(w2[(fbase + 0) * 64 + g]);
                u16 a1 = f2bf(w2[(fbase + 1) * 64 + g]);
                u16 a2 = f2bf(w2[(fbase + 2) * 64 + g]);
                u16 a3 = f2bf(w2[(fbase + 3) * 64 + g]);
                uint2 ov;
                ov.x = (u32)a0 | ((u32)a1 << 16);
                ov.y = (u32)a2 | ((u32)a3 << 16);
                *(uint2*)(dstrow + pos * 4) = ov;
            }
        }
        return;
    }

    if (bi < 1216) {
        // ---- cvt role: o_w fp32 -> bf16 ----
        int i = (bi - 192) * 256 + tid;      // exactly 1024*256 = 262144 float4s
        float4 v = ((const float4*)ow)[i];
        unsigned int lov = (unsigned int)f2bf(v.x) | ((unsigned int)f2bf(v.y) << 16);
        unsigned int hiv = (unsigned int)f2bf(v.z) | ((unsigned int)f2bf(v.w) << 16);
        ((uint2*)owbf)[i] = make_uint2(lov, hiv);
        return;
    }

    if (bi < 1472) {
        // ---- router role ----
        const unsigned int g = (bi - 1216) * 256 + tid;

        __shared__ float rS[3][64][8];
        __shared__ int lcnt[192];
        __shared__ int lbase[192];

        for (int i = tid; i < 1536; i += 256) {
            int p = i >> 9, rem = i & 511;
            const float* rp = (p == 0) ? rq : (p == 1) ? rk : rv;
            rS[p][rem >> 3][rem & 7] = rp[rem];
        }
        if (tid < 192) lcnt[tid] = 0;
        __syncthreads();

        float lg[3][8];
        #pragma unroll
        for (int p = 0; p < 3; ++p)
            #pragma unroll
            for (int e = 0; e < 8; ++e) lg[p][e] = 0.f;

        const float* xr = x + (size_t)g * 64;
        for (int i4 = 0; i4 < 16; ++i4) {
            float4 xv = ((const float4*)xr)[i4];
            float xa[4] = {xv.x, xv.y, xv.z, xv.w};
            #pragma unroll
            for (int m = 0; m < 4; ++m) {
                int d = i4 * 4 + m;
                #pragma unroll
                for (int p = 0; p < 3; ++p) {
                    float4 r0 = *(const float4*)&rS[p][d][0];
                    float4 r1 = *(const float4*)&rS[p][d][4];
                    lg[p][0] += xa[m] * r0.x; lg[p][1] += xa[m] * r0.y;
                    lg[p][2] += xa[m] * r0.z; lg[p][3] += xa[m] * r0.w;
                    lg[p][4] += xa[m] * r1.x; lg[p][5] += xa[m] * r1.y;
                    lg[p][6] += xa[m] * r1.z; lg[p][7] += xa[m] * r1.w;
                }
            }
        }

        int ppe[3]; float2 pw[3]; int slot[3];
        #pragma unroll
        for (int p = 0; p < 3; ++p) {
            int i1 = 0; float v1 = lg[p][0];
            #pragma unroll
            for (int e = 1; e < 8; ++e) { if (lg[p][e] > v1) { v1 = lg[p][e]; i1 = e; } }
            int i2 = -1; float v2 = -3.402823466e38f;
            #pragma unroll
            for (int e = 0; e < 8; ++e) { if (e != i1 && lg[p][e] > v2) { v2 = lg[p][e]; i2 = e; } }
            float z = __expf(v2 - v1);
            float inv = 1.f / (1.f + z);
            float wa = inv, wb = z * inv;
            int lo = min(i1, i2), hi = max(i1, i2);
            float wlo = (i1 < i2) ? wa : wb;
            float whi = (i1 < i2) ? wb : wa;
            int pel = p * 64 + lo * 8 + hi;
            ppe[p] = pel; pw[p] = make_float2(wlo, whi);
            slot[p] = atomicAdd(&lcnt[pel], 1);
        }
        __syncthreads();
        if (tid < 192) {
            int c = lcnt[tid];
            lbase[tid] = c ? (int)atomicAdd(&counts[tid], (unsigned int)c) : 0;
        }
        __syncthreads();
        #pragma unroll
        for (int p = 0; p < 3; ++p) {
            int pos = lbase[ppe[p]] + slot[p];
            if (pos < CAP) {
                idxbuf[ppe[p] * CAP + pos] = g;
                wtbuf[ppe[p] * CAP + pos]  = pw[p];
            }
        }
        return;
    }

    // ---- xcvt role: x fp32 -> bf16 (fast round, coalesced 16B stores) ----
    {
        int i = (bi - 1472) * 256 + tid;     // 524288 threads x 8 floats
        float4 v0 = ((const float4*)x)[2 * i];
        float4 v1 = ((const float4*)x)[2 * i + 1];
        uint4 ov;
        ov.x = pkbf(v0.x, v0.y);
        ov.y = pkbf(v0.z, v0.w);
        ov.z = pkbf(v1.x, v1.y);
        ov.w = pkbf(v1.z, v1.w);
        ((uint4*)xbf)[i] = ov;
    }
}

// ============================================================================
// Kernel 1b: scheduler. Allocates GEXP blocks across the 84 (proj,pair)
// lists proportionally to subtile count (largest-remainder).
// ============================================================================
__global__ __launch_bounds__(128) void sched_kernel(
    const unsigned int* __restrict__ counts, unsigned int* __restrict__ blockinfo)
{
    const int tid = threadIdx.x;
    __shared__ int nsub[84];
    __shared__ int extra[84];
    __shared__ int frac[84];
    __shared__ int alloc[84];
    __shared__ int startS[84];
    __shared__ int nnzS, totalS, rem2S;

    if (tid < 84) {
        int p = tid / 28, q = tid - 28 * p, lo = 0;
        while (q >= 7 - lo) { q -= 7 - lo; ++lo; }
        int hi = lo + 1 + q;
        int n = (int)counts[p * 64 + lo * 8 + hi];
        if (n > CAP) n = CAP;
        nsub[tid] = (n + 31) >> 5;
    }
    __syncthreads();
    if (tid == 0) {
        int tot = 0, nz = 0;
        for (int i = 0; i < 84; ++i) { tot += nsub[i]; nz += (nsub[i] > 0); }
        totalS = tot; nnzS = nz;
    }
    __syncthreads();
    const int R = GEXP - nnzS;
    if (tid < 84) {
        if (nsub[tid] > 0) {
            int e = (int)(((long long)nsub[tid] * R) / totalS);
            extra[tid] = e;
            frac[tid] = nsub[tid] * R - e * totalS;
        } else { extra[tid] = 0; frac[tid] = -1; }
    }
    __syncthreads();
    if (tid == 0) {
        int se = 0;
        for (int i = 0; i < 84; ++i) se += extra[i];
        rem2S = GEXP - nnzS - se;
    }
    __syncthreads();
    if (tid < 84) {
        if (nsub[tid] > 0) {
            int rank = 0;
            for (int j = 0; j < 84; ++j)
                if (nsub[j] > 0 && (frac[j] > frac[tid] || (frac[j] == frac[tid] && j < tid))) ++rank;
            alloc[tid] = 1 + extra[tid] + (rank < rem2S ? 1 : 0);
        } else alloc[tid] = 0;
    }
    __syncthreads();
    if (tid == 0) {
        int s = 0;
        for (int i = 0; i < 84; ++i) { startS[i] = s; s += alloc[i]; }
    }
    __syncthreads();
    if (tid < 84) {
        int a = alloc[tid], st = startS[tid];
        for (int c = 0; c < a; ++c)
            blockinfo[st + c] = (unsigned)tid | ((unsigned)c << 8) | ((unsigned)a << 20);
    }
}

// ============================================================================
// Kernel 2: pair-grouped expert MLP, bf16 MFMA, wave-independent.
// GEXP=504, bf16 x gather + packed gelu, rolled ekk loop. (R13 config.)
// ============================================================================
__global__ __launch_bounds__(512, 2) void expert_kernel(
    const u16* __restrict__ xbf, const int* __restrict__ pos_ids,
    const float* __restrict__ cosb, const float* __restrict__ sinb,
    const u16* __restrict__ img1, const u16* __restrict__ img2,
    const unsigned int* __restrict__ counts,
    const unsigned int* __restrict__ idxbuf, const float2* __restrict__ wtbuf,
    const unsigned int* __restrict__ blockinfo,
    u16* __restrict__ qb, u16* __restrict__ kb, u16* __restrict__ vb)
{
    const int tid = threadIdx.x;
    const unsigned int info = blockinfo[blockIdx.x];
    const int pe84 = info & 255;
    const int chunk = (info >> 8) & 0xFFF;
    const int nch = info >> 20;
    const int p = pe84 / 28;
    int q28 = pe84 - p * 28;
    int lo = 0;
    while (q28 >= 7 - lo) { q28 -= 7 - lo; ++lo; }
    const int hi = lo + 1 + q28;
    const int pe = p * 64 + lo * 8 + hi;

    int n = (int)counts[pe]; if (n == 0) return; if (n > CAP) n = CAP;

    u16* outp = (p == 0) ? qb : (p == 1) ? kb : vb;
    const unsigned int* il = idxbuf + pe * CAP;
    const float2* wl = wtbuf + pe * CAP;

    __shared__ __align__(16) u16 wsh[32768];   // [e]{ w1 8192 | w2 8192 }  64 KB

    {   // linear DMA staging: images are byte-identical to LDS layout
        const u16* a0 = img1 + (p * 8 + lo) * 8192;
        const u16* b0 = img2 + (p * 8 + lo) * 8192;
        const u16* a1 = img1 + (p * 8 + hi) * 8192;
        const u16* b1 = img2 + (p * 8 + hi) * 8192;
        #pragma unroll
        for (int k = 0; k < 2; ++k) {
            int o = (k * 512 + tid) * 8;
            GLD16(a0 + o, wsh + o);
            GLD16(b0 + o, wsh + 8192 + o);
            GLD16(a1 + o, wsh + 16384 + o);
            GLD16(b1 + o, wsh + 24576 + o);
        }
    }
    __syncthreads();

    const int lane = tid & 63, w = tid >> 6, quad = lane >> 4, m16 = lane & 15;
    const int f7 = m16 & 7;
    const int wid = chunk * 8 + w;
    const int WRK = nch * 8;
    const int nsub = (n + 31) >> 5;

    for (int s = wid; s < nsub; s += WRK) {
        const int base = s * 32;
        unsigned int gtok = 0, obase = 0; float wlo_ = 0.f, whi_ = 0.f;
        int posv = 0, valid = 0;
        if (lane < 32) {
            int j = base + lane;
            valid = (j < n);
            int jc = valid ? j : (n - 1);
            gtok = il[jc];
            float2 wv = wl[jc];
            wlo_ = valid ? wv.x : 0.f; whi_ = valid ? wv.y : 0.f;
            unsigned int b_ = gtok >> 14, h_ = gtok & 15, t_ = (gtok >> 4) & 1023;
            obase = ((b_ * 16 + h_) * 1024 + t_) * 64;
            posv = pos_ids[b_ * 1024 + t_];
        }

        // per-(e, mt2) router weight for this lane's token column (m16)
        float wf00 = __shfl(wlo_, m16, 64);
        float wf10 = __shfl(whi_, m16, 64);
        float wf01 = __shfl(wlo_, 16 + m16, 64);
        float wf11 = __shfl(whi_, 16 + m16, 64);

        bf16x8 Afr[2][2];
        #pragma unroll
        for (int mt2 = 0; mt2 < 2; ++mt2) {
            unsigned int gm = (unsigned int)__shfl((int)gtok, mt2 * 16 + m16, 64);
            const u16* xr = xbf + (size_t)gm * 64 + 8 * quad;
            Afr[mt2][0] = *(const bf16x8*)(xr);
            Afr[mt2][1] = *(const bf16x8*)(xr + 32);
        }

        f32x4 acc2[2][4];   // [mt2][nt2] — out'[g][tok], router weights pre-folded
        #pragma unroll
        for (int mt2 = 0; mt2 < 2; ++mt2)
            #pragma unroll
            for (int nt = 0; nt < 4; ++nt) acc2[mt2][nt] = (f32x4){0.f, 0.f, 0.f, 0.f};

        // Rolled loop over (e, kk): 8 iterations, body unrolled inside.
        #pragma unroll 1
        for (int ekk = 0; ekk < 8; ++ekk) {
            const int e = ekk >> 2;
            const int kk = ekk & 3;
            const u16* w1b = wsh + e * 16384;
            const u16* w2b = w1b + 8192;
            const float wt0 = e ? wf10 : wf00;
            const float wt1 = e ? wf11 : wf01;

            // --- GEMM1 swapped: C'[f][tok], row=f(4*quad+r), col=tok(m16)
            f32x4 c[2][2];   // [ntl][mt2]
            #pragma unroll
            for (int ntl = 0; ntl < 2; ++ntl) {
                const int f = 16 * (2 * kk + ntl) + m16;
                const u16* w1f = w1b + f * 64;
                bf16x8 wa = *(const bf16x8*)(w1f + (((quad    ) ^ f7) << 3));
                bf16x8 wb = *(const bf16x8*)(w1f + (((quad + 4) ^ f7) << 3));
                #pragma unroll
                for (int mt2 = 0; mt2 < 2; ++mt2) {
                    f32x4 t = (f32x4){0.f, 0.f, 0.f, 0.f};
                    t = __builtin_amdgcn_mfma_f32_16x16x32_bf16(wa, Afr[mt2][0], t, 0, 0, 0);
                    c[ntl][mt2] = __builtin_amdgcn_mfma_f32_16x16x32_bf16(wb, Afr[mt2][1], t, 0, 0, 0);
                }
            }

            // --- A2 (w2^T) K=16 fragments: mt2-invariant, loaded once
            bf16x4 w2f[2][4];   // [ntl][nt2]
            #pragma unroll
            for (int ntl = 0; ntl < 2; ++ntl) {
                const int gg = 4 * (2 * kk + ntl) + quad;
                #pragma unroll
                for (int nt2 = 0; nt2 < 4; ++nt2) {
                    const int g = 16 * nt2 + m16;
                    const int pos = gg ^ (g & 31);
                    w2f[ntl][nt2] = *(const bf16x4*)(w2b + g * 128 + pos * 4);
                }
            }

            // --- packed gelu+scale, pack to bf16, GEMM2 = mfma16(w2^T, h)
            #pragma unroll
            for (int mt2 = 0; mt2 < 2; ++mt2) {
                const float wt = mt2 ? wt1 : wt0;
                #pragma unroll
                for (int ntl = 0; ntl < 2; ++ntl) {
                    f32x2 z01 = {c[ntl][mt2][0], c[ntl][mt2][1]};
                    f32x2 z23 = {c[ntl][mt2][2], c[ntl][mt2][3]};
                    f32x2 g01 = gelu2w(z01, wt);
                    f32x2 g23 = gelu2w(z23, wt);
                    union { u32 u[2]; bf16x4 v; } bf_;
                    bf_.u[0] = pkbf(g01.x, g01.y);
                    bf_.u[1] = pkbf(g23.x, g23.y);
                    #pragma unroll
                    for (int nt2 = 0; nt2 < 4; ++nt2)
                        acc2[mt2][nt2] = __builtin_amdgcn_mfma_f32_16x16x16bf16_1k(
                            w2f[ntl][nt2], bf_.v, acc2[mt2][nt2], 0, 0, 0);
                }
            }
        }

        // Epilogue: lane (quad,m16) owns token mt2*16+m16, g = 16*nt2+4*quad+reg.
        #pragma unroll
        for (int mt2 = 0; mt2 < 2; ++mt2) {
            const int tk = mt2 * 16 + m16;
            int   pos_r = __shfl(posv, tk, 64);
            unsigned int ob = (unsigned int)__shfl((int)obase, tk, 64);
            int   val_r = __shfl(valid, tk, 64);
            if (p < 2) {
                #pragma unroll
                for (int ntp = 0; ntp < 2; ++ntp) {
                    const int d0 = 16 * ntp + 4 * quad;
                    float4 cv = *(const float4*)&cosb[pos_r * 64 + d0];
                    float4 sv = *(const float4*)&sinb[pos_r * 64 + d0];
                    float o1[4], o2[4];
                    #pragma unroll
                    for (int r = 0; r < 4; ++r) {
                        float v1 = acc2[mt2][ntp][r];
                        float v2 = acc2[mt2][ntp + 2][r];
                        float cd = (&cv.x)[r], sd = (&sv.x)[r];
                        o1[r] = v1 * cd - v2 * sd;
                        o2[r] = v2 * cd + v1 * sd;
                    }
                    if (val_r) {
                        uint2 s1, s2;
                        s1.x = (u32)f2bf(o1[0]) | ((u32)f2bf(o1[1]) << 16);
                        s1.y = (u32)f2bf(o1[2]) | ((u32)f2bf(o1[3]) << 16);
                        s2.x = (u32)f2bf(o2[0]) | ((u32)f2bf(o2[1]) << 16);
                        s2.y = (u32)f2bf(o2[2]) | ((u32)f2bf(o2[3]) << 16);
                        *(uint2*)&outp[ob + d0]      = s1;
                        *(uint2*)&outp[ob + d0 + 32] = s2;
                    }
                }
            } else {
                if (val_r) {
                    #pragma unroll
                    for (int nt2 = 0; nt2 < 4; ++nt2) {
                        uint2 s1;
                        s1.x = (u32)f2bf(acc2[mt2][nt2][0]) | ((u32)f2bf(acc2[mt2][nt2][1]) << 16);
                        s1.y = (u32)f2bf(acc2[mt2][nt2][2]) | ((u32)f2bf(acc2[mt2][nt2][3]) << 16);
                        *(uint2*)&outp[ob + 16 * nt2 + 4 * quad] = s1;
                    }
                }
            }
        }
    }
}

// ============================================================================
// Kernel 4: flash attention. Swapped QK^T (S^T layout), in-register P^T,
// PV via mfma16(V^T, P^T), base-2 softmax via raw v_exp_f32, double-buffered
// K/V LDS (one barrier/iter). Paired q-tiles.
// ============================================================================
__global__ __launch_bounds__(256) void attn_kernel(
    const u16* __restrict__ qbp, const u16* __restrict__ kbp,
    const u16* __restrict__ vbp, u16* __restrict__ ao)
{
    const int tid = threadIdx.x;
    const int i8 = blockIdx.x & 7;
    const int plane_i = blockIdx.x >> 3;           // 64 planes
    const int h = plane_i & 15, b = plane_i >> 4;
    const size_t plane = (size_t)plane_i * 1024 * 64;
    const u16* qp = qbp + plane;
    const u16* kp = kbp + plane;
    const u16* vp = vbp + plane;

    const int w = tid >> 6, lane = tid & 63, quad = lane >> 4, m16 = lane & 15;
    const int row = tid >> 2, seg = tid & 3;       // K staging coords
    const int kjv = tid & 63, dgv = tid >> 6;      // V staging coords

    __shared__ u16 Ks[2][64][72];
    __shared__ u16 Vt[2][64][72];     // [buf][d][kj]
    __shared__ u16 Ps[4][16][72];     // per-wave O^T transpose scratch

    #pragma unroll 1
    for (int half = 0; half < 2; ++half) {
        const int qt = half ? (15 - i8) : i8;
        const int q0 = qt * 64;

        const u16* qrow = &qp[(size_t)(q0 + 16 * w + m16) * 64 + 8 * quad];
        bf16x8 aq0 = *(const bf16x8*)(qrow);
        bf16x8 aq1 = *(const bf16x8*)(qrow + 32);

        uint4 kr0, kr1; ushort4 vr0, vr1, vr2, vr3;
        {   // load tile 0 and commit straight to buf0
            const uint4* src = (const uint4*)&kp[(size_t)row * 64 + seg * 16];
            kr0 = src[0]; kr1 = src[1];
            const u16* vb2 = &vp[(size_t)kjv * 64 + dgv * 4];
            vr0 = *(const ushort4*)(vb2);
            vr1 = *(const ushort4*)(vb2 + 16);
            vr2 = *(const ushort4*)(vb2 + 32);
            vr3 = *(const ushort4*)(vb2 + 48);
            uint4* dst = (uint4*)&Ks[0][row][seg * 16];
            dst[0] = kr0; dst[1] = kr1;
            int d0 = dgv * 4;
            Vt[0][d0 + 0][kjv] = vr0.x; Vt[0][d0 + 1][kjv] = vr0.y;
            Vt[0][d0 + 2][kjv] = vr0.z; Vt[0][d0 + 3][kjv] = vr0.w;
            Vt[0][d0 + 16][kjv] = vr1.x; Vt[0][d0 + 17][kjv] = vr1.y;
            Vt[0][d0 + 18][kjv] = vr1.z; Vt[0][d0 + 19][kjv] = vr1.w;
            Vt[0][d0 + 32][kjv] = vr2.x; Vt[0][d0 + 33][kjv] = vr2.y;
            Vt[0][d0 + 34][kjv] = vr2.z; Vt[0][d0 + 35][kjv] = vr2.w;
            Vt[0][d0 + 48][kjv] = vr3.x; Vt[0][d0 + 49][kjv] = vr3.y;
            Vt[0][d0 + 50][kjv] = vr3.z; Vt[0][d0 + 51][kjv] = vr3.w;
        }
        if (qt > 0) {   // preload tile 1 into registers
            const uint4* src = (const uint4*)&kp[(size_t)(64 + row) * 64 + seg * 16];
            kr0 = src[0]; kr1 = src[1];
            const u16* vb2 = &vp[(size_t)(64 + kjv) * 64 + dgv * 4];
            vr0 = *(const ushort4*)(vb2);
            vr1 = *(const ushort4*)(vb2 + 16);
            vr2 = *(const ushort4*)(vb2 + 32);
            vr3 = *(const ushort4*)(vb2 + 48);
        }
        __syncthreads();

        float m_s = -1e30f, l_s = 0.f;     // this lane's q = 16*w + m16
        f32x4 oacc[4];                     // O^T[d = 16*dt + 4*quad + reg][q]
        #pragma unroll
        for (int i = 0; i < 4; ++i) oacc[i] = (f32x4){0.f, 0.f, 0.f, 0.f};

        const int qrow_l = 16 * w + m16;   // tile-local q row of this lane

        for (int kt = 0; kt <= qt; ++kt) {
            const int cur = kt & 1;
            if (kt < qt) {   // commit prefetched tile kt+1 to the other buffer
                const int nxt = cur ^ 1;     // overlaps with compute below
                uint4* dst = (uint4*)&Ks[nxt][row][seg * 16];
                dst[0] = kr0; dst[1] = kr1;
                int d0 = dgv * 4;
                Vt[nxt][d0 + 0][kjv] = vr0.x; Vt[nxt][d0 + 1][kjv] = vr0.y;
                Vt[nxt][d0 + 2][kjv] = vr0.z; Vt[nxt][d0 + 3][kjv] = vr0.w;
                Vt[nxt][d0 + 16][kjv] = vr1.x; Vt[nxt][d0 + 17][kjv] = vr1.y;
                Vt[nxt][d0 + 18][kjv] = vr1.z; Vt[nxt][d0 + 19][kjv] = vr1.w;
                Vt[nxt][d0 + 32][kjv] = vr2.x; Vt[nxt][d0 + 33][kjv] = vr2.y;
                Vt[nxt][d0 + 34][kjv] = vr2.z; Vt[nxt][d0 + 35][kjv] = vr2.w;
                Vt[nxt][d0 + 48][kjv] = vr3.x; Vt[nxt][d0 + 49][kjv] = vr3.y;
                Vt[nxt][d0 + 50][kjv] = vr3.z; Vt[nxt][d0 + 51][kjv] = vr3.w;
                if (kt + 1 < qt) {   // load tile kt+2 into registers
                    const int k0n = (kt + 2) * 64;
                    const uint4* src = (const uint4*)&kp[(size_t)(k0n + row) * 64 + seg * 16];
                    kr0 = src[0]; kr1 = src[1];
                    const u16* vb2 = &vp[(size_t)(k0n + kjv) * 64 + dgv * 4];
                    vr0 = *(const ushort4*)(vb2);
                    vr1 = *(const ushort4*)(vb2 + 16);
                    vr2 = *(const ushort4*)(vb2 + 32);
                    vr3 = *(const ushort4*)(vb2 + 48);
                }
            }

            // QK^T swapped: S^T[k = 16ct + 4quad + reg][q = 16w + m16]
            f32x4 sv[4];
            #pragma unroll
            for (int ct = 0; ct < 4; ++ct) {
                bf16x8 bk0 = *(const bf16x8*)&Ks[cur][16 * ct + m16][8 * quad];
                bf16x8 bk1 = *(const bf16x8*)&Ks[cur][16 * ct + m16][32 + 8 * quad];
                f32x4 acc = (f32x4){0.f, 0.f, 0.f, 0.f};
                acc = __builtin_amdgcn_mfma_f32_16x16x32_bf16(bk0, aq0, acc, 0, 0, 0);
                acc = __builtin_amdgcn_mfma_f32_16x16x32_bf16(bk1, aq1, acc, 0, 0, 0);
                sv[ct] = acc;
            }

            float s[4][4];
            const bool diag = (kt == qt);
            #pragma unroll
            for (int ct = 0; ct < 4; ++ct)
                #pragma unroll
                for (int reg = 0; reg < 4; ++reg) {
                    float v = sv[ct][reg] * 0.18033688f;   // 0.125 * log2(e)
                    if (diag) {
                        int krow = 16 * ct + 4 * quad + reg;
                        if (krow > qrow_l) v = -1e30f;
                    }
                    s[ct][reg] = v;
                }

            // softmax per q (base-2): lane-local 16-max + 2 shuffles across quad
            float rm = s[0][0];
            #pragma unroll
            for (int ct = 0; ct < 4; ++ct)
                #pragma unroll
                for (int reg = 0; reg < 4; ++reg) rm = fmaxf(rm, s[ct][reg]);
            rm = fmaxf(rm, __shfl_xor(rm, 16, 64));
            rm = fmaxf(rm, __shfl_xor(rm, 32, 64));
            float mn = fmaxf(m_s, rm);
            float al = exp2_raw(m_s - mn);
            float sum = 0.f;
            #pragma unroll
            for (int ct = 0; ct < 4; ++ct)
                #pragma unroll
                for (int reg = 0; reg < 4; ++reg) {
                    float pv = exp2_raw(s[ct][reg] - mn);
                    s[ct][reg] = pv;
                    sum += pv;
                }
            sum += __shfl_xor(sum, 16, 64);
            sum += __shfl_xor(sum, 32, 64);
            l_s = l_s * al + sum;
            m_s = mn;

            // P^T bf16 fragments (K=16 B-operand), in-register
            bf16x4 pt[4];
            #pragma unroll
            for (int ct = 0; ct < 4; ++ct) {
                union { u32 u[2]; bf16x4 v; } pb;
                pb.u[0] = pkbf(s[ct][0], s[ct][1]);
                pb.u[1] = pkbf(s[ct][2], s[ct][3]);
                pt[ct] = pb.v;
            }

            #pragma unroll
            for (int dt = 0; dt < 4; ++dt)
                #pragma unroll
                for (int reg = 0; reg < 4; ++reg) oacc[dt][reg] *= al;

            // PV: O^T[d][q] += V^T_frag x P^T_frag  (K=16 per k-strip ct)
            #pragma unroll
            for (int dt = 0; dt < 4; ++dt) {
                #pragma unroll
                for (int ct = 0; ct < 4; ++ct) {
                    bf16x4 vf = *(const bf16x4*)&Vt[cur][16 * dt + m16][16 * ct + 4 * quad];
                    oacc[dt] = __builtin_amdgcn_mfma_f32_16x16x16bf16_1k(vf, pt[ct], oacc[dt], 0, 0, 0);
                }
            }

            __syncthreads();   // buf[cur] reads done; buf[cur^1] writes visible
        }

        // O^T -> O transpose via per-wave LDS scratch, then coalesced store
        float linv = 1.f / l_s;
        #pragma unroll
        for (int dt = 0; dt < 4; ++dt) {
            u32 lo = (u32)f2bf(oacc[dt][0] * linv) | ((u32)f2bf(oacc[dt][1] * linv) << 16);
            u32 hi = (u32)f2bf(oacc[dt][2] * linv) | ((u32)f2bf(oacc[dt][3] * linv) << 16);
            *(u32*)&Ps[w][m16][16 * dt + 4 * quad]     = lo;
            *(u32*)&Ps[w][m16][16 * dt + 4 * quad + 2] = hi;
        }
        __syncthreads();
        #pragma unroll
        for (int reg = 0; reg < 4; ++reg) {
            int rw = q0 + 16 * w + 4 * quad + reg;
            size_t base = ((size_t)(b * 1024) + rw) * 1024 + h * 64;
            #pragma unroll
            for (int dt = 0; dt < 4; ++dt)
                ao[base + 16 * dt + m16] = Ps[w][4 * quad + reg][16 * dt + m16];
        }
        __syncthreads();   // Ps reads done before next half reuses buffers
    }
}

// ============================================================================
// Kernel 5: output projection, bf16 MFMA gemm_bt. 128x64 tiles, 512 blocks
// (2/CU, 8 waves/CU), register-prefetch pipeline, LDS rows padded to 40 u16.
// ============================================================================
__global__ __launch_bounds__(256) void oproj_kernel(
    const u16* __restrict__ A, const u16* __restrict__ Bw,
    float* __restrict__ out)
{
    const int tid = threadIdx.x;
    const int bn = blockIdx.x & 15;
    const int bm = blockIdx.x >> 4;
    const int m0 = bm * 128, n0 = bn * 64;
    const int w = tid >> 6, lane = tid & 63, quad = lane >> 4, m16 = lane & 15;
    const int wm = (w >> 1) * 64, wn = (w & 1) * 32;

    __shared__ u16 As[128][40];
    __shared__ u16 Bs[64][40];

    const int arw = tid >> 1, asg = (tid & 1) * 16;
    const int brw = tid >> 2, bsg = (tid & 3) * 8;
    const u16* srcA = A + (size_t)(m0 + arw) * 1024 + asg;
    const u16* srcB = Bw + (size_t)(n0 + brw) * 1024 + bsg;

    f32x4 acc[4][2];
    #pragma unroll
    for (int mt = 0; mt < 4; ++mt)
        #pragma unroll
        for (int nt = 0; nt < 2; ++nt) acc[mt][nt] = (f32x4){0.f, 0.f, 0.f, 0.f};

    uint4 pa0 = ((const uint4*)srcA)[0];
    uint4 pa1 = ((const uint4*)srcA)[1];
    uint4 pb0 = *(const uint4*)srcB;

    for (int k0 = 0; k0 < 1024; k0 += 32) {
        __syncthreads();
        *(uint4*)&As[arw][asg]     = pa0;
        *(uint4*)&As[arw][asg + 8] = pa1;
        *(uint4*)&Bs[brw][bsg]     = pb0;
        __syncthreads();
        if (k0 + 32 < 1024) {
            pa0 = ((const uint4*)(srcA + k0 + 32))[0];
            pa1 = ((const uint4*)(srcA + k0 + 32))[1];
            pb0 = *(const uint4*)(srcB + k0 + 32);
        }
        bf16x8 af[4], bfr[2];
        #pragma unroll
        for (int mt = 0; mt < 4; ++mt) af[mt] = *(const bf16x8*)&As[wm + 16 * mt + m16][8 * quad];
        #pragma unroll
        for (int nt = 0; nt < 2; ++nt) bfr[nt] = *(const bf16x8*)&Bs[wn + 16 * nt + m16][8 * quad];
        #pragma unroll
        for (int mt = 0; mt < 4; ++mt)
            #pragma unroll
            for (int nt = 0; nt < 2; ++nt)
                acc[mt][nt] = __builtin_amdgcn_mfma_f32_16x16x32_bf16(af[mt], bfr[nt], acc[mt][nt], 0, 0, 0);
    }
    #pragma unroll
    for (int mt = 0; mt < 4; ++mt)
        #pragma unroll
        for (int nt = 0; nt < 2; ++nt)
            #pragma unroll
            for (int reg = 0; reg < 4; ++reg)
                out[(size_t)(m0 + wm + 16 * mt + 4 * quad + reg) * 1024 + n0 + wn + 16 * nt + m16] =
                    acc[mt][nt][reg];
}

// ============================================================================
extern "C" void kernel_launch(void* const* d_in, const int* in_sizes, int n_in,
                              void* d_out, int out_size, void* d_ws, size_t ws_size,
                              hipStream_t stream) {
    (void)in_sizes; (void)n_in; (void)out_size; (void)ws_size;
    const float* x    = (const float*)d_in[0];
    const int*   pid  = (const int*)  d_in[1];
    const float* cosb = (const float*)d_in[2];
    const float* sinb = (const float*)d_in[3];
    const float* rq   = (const float*)d_in[4];
    const float* rk   = (const float*)d_in[5];
    const float* rv   = (const float*)d_in[6];
    const float* qw1  = (const float*)d_in[7];
    const float* qw2  = (const float*)d_in[8];
    const float* kw1  = (const float*)d_in[9];
    const float* kw2  = (const float*)d_in[10];
    const float* vw1  = (const float*)d_in[11];
    const float* vw2  = (const float*)d_in[12];
    const float* ow   = (const float*)d_in[13];
    float* out = (float*)d_out;

    const size_t MB = 1u << 20;
    char* wsb = (char*)d_ws;
    u16* qb   = (u16*)(wsb + 0 * MB);      // 8 MB  bf16 [B,H,T,D]
    u16* kb   = (u16*)(wsb + 8 * MB);      // 8 MB
    u16* vb   = (u16*)(wsb + 16 * MB);     // 8 MB
    // xbf and aobf SHARE [24,32) MB: prep writes xbf -> expert reads xbf ->
    // attn overwrites region with aobf -> oproj reads aobf. Strictly ordered
    // on one stream, so no conflict (saves 8 MB of workspace).
    u16* xbf  = (u16*)(wsb + 24 * MB);     // 8 MB  bf16 x  [B,T,C]
    u16* aobf = (u16*)(wsb + 24 * MB);     // 8 MB  bf16 attn-out [B,T,C]
    u16* owbf = (u16*)(wsb + 32 * MB);     // 2 MB  bf16 o_w
    unsigned int* idxbuf = (unsigned int*)(wsb + 34 * MB);       // 6 MB
    float2*       wtbuf  = (float2*)(wsb + 41 * MB);             // 12 MB
    unsigned int* counts = (unsigned int*)(wsb + 54 * MB);       // 768 B
    unsigned int* blockinfo = (unsigned int*)(wsb + 54 * MB + 4096); // 2 KB
    u16* w1img = (u16*)(wsb + 56 * MB);    // 384 KB  bf16 w1 LDS images
    u16* w2img = (u16*)(wsb + 57 * MB);    // 384 KB  bf16 w2^T LDS images

    hipMemsetAsync(counts, 0, 1024, stream);

    hipLaunchKernelGGL(prep_kernel, dim3(3520), dim3(256), 0, stream,
                       x, rq, rk, rv, counts, idxbuf, wtbuf,
                       qw1, kw1, vw1, qw2, kw2, vw2, w1img, w2img,
                       ow, owbf, xbf);
    hipLaunchKernelGGL(sched_kernel, dim3(1), dim3(128), 0, stream,
                       counts, blockinfo);
    hipLaunchKernelGGL(expert_kernel, dim3(GEXP), dim3(512), 0, stream,
                       xbf, pid, cosb, sinb, w1img, w2img,
                       counts, idxbuf, wtbuf, blockinfo, qb, kb, vb);
    hipLaunchKernelGGL(attn_kernel, dim3(512), dim3(256), 0, stream,
                       qb, kb, vb, aobf);
    hipLaunchKernelGGL(oproj_kernel, dim3(512), dim3(256), 0, stream,
                       aobf, owbf, out);
}